// Round 2
// baseline (968.523 us; speedup 1.0000x reference)
//
#include <hip/hip_runtime.h>
#include <math.h>

typedef short bf16x8 __attribute__((ext_vector_type(8)));
typedef float f32x4 __attribute__((ext_vector_type(4)));

__device__ __forceinline__ short f2bf(float f) {
    union { float f; unsigned u; } v; v.f = f;
    unsigned r = v.u + 0x7fffu + ((v.u >> 16) & 1u);
    return (short)(r >> 16);
}

// shifted softplus: 2*log(1+exp(0.5x)); stable form matches reference's
// threshold-14 passthrough to ~2e-6
__device__ __forceinline__ float ssp(float x) {
    float h = 0.5f * x;
    return 2.0f * (fmaxf(h, 0.0f) + __logf(1.0f + __expf(-fabsf(h))));
}

// ---------- counting sort by dst: histogram -> scan -> permutation ----------

__global__ void hist_kernel(const int* __restrict__ dst, int n, int* __restrict__ cnt) {
    int i = blockIdx.x * 256 + threadIdx.x;
    if (i < n) atomicAdd(&cnt[dst[i]], 1);
}

__global__ void blocksum_kernel(const int* __restrict__ cnt, int n, int* __restrict__ partials) {
    __shared__ int red[256];
    int t = threadIdx.x, base = blockIdx.x * 1024 + t * 4, s = 0;
    #pragma unroll
    for (int j = 0; j < 4; ++j) { int i = base + j; if (i < n) s += cnt[i]; }
    red[t] = s; __syncthreads();
    for (int off = 128; off > 0; off >>= 1) {
        if (t < off) red[t] += red[t + off];
        __syncthreads();
    }
    if (t == 0) partials[blockIdx.x] = red[0];
}

__global__ void scanpart_kernel(int* __restrict__ partials, int nb) {
    __shared__ int buf[256];
    int t = threadIdx.x;
    if (t < nb) buf[t] = partials[t];
    __syncthreads();
    if (t == 0) { int run = 0; for (int i = 0; i < nb; ++i) { int v = buf[i]; buf[i] = run; run += v; } }
    __syncthreads();
    if (t < nb) partials[t] = buf[t];
}

__global__ void scanwrite_kernel(const int* __restrict__ cnt, int n,
                                 const int* __restrict__ partials, int* __restrict__ cursor) {
    __shared__ int sc[256];
    int t = threadIdx.x, b = blockIdx.x, base = b * 1024 + t * 4;
    int v[4], s = 0;
    #pragma unroll
    for (int j = 0; j < 4; ++j) { int i = base + j; v[j] = (i < n) ? cnt[i] : 0; s += v[j]; }
    sc[t] = s; __syncthreads();
    for (int off = 1; off < 256; off <<= 1) {          // in-place Hillis-Steele inclusive scan
        int y = (t >= off) ? sc[t - off] : 0;
        __syncthreads();
        sc[t] += y;
        __syncthreads();
    }
    int run = partials[b] + sc[t] - s;                  // exclusive prefix for this thread
    #pragma unroll
    for (int j = 0; j < 4; ++j) { int i = base + j; if (i < n) cursor[i] = run; run += v[j]; }
}

__global__ void perm_kernel(const int* __restrict__ dst, int n,
                            int* __restrict__ cursor, int* __restrict__ perm) {
    int i = blockIdx.x * 256 + threadIdx.x;
    if (i < n) { int p = atomicAdd(&cursor[dst[i]], 1); perm[p] = i; }
}

// ---------------------------- fused main kernel ----------------------------

__global__ __launch_bounds__(256, 2) void cfconv_kernel(
    const float* __restrict__ nw, const float* __restrict__ rbf,
    const float* __restrict__ W1, const float* __restrict__ b1,
    const float* __restrict__ W2, const float* __restrict__ b2,
    const int* __restrict__ src, const int* __restrict__ dst,
    const int* __restrict__ perm, float* __restrict__ out,
    int n_edges, int ntiles, int tiles_per_wave)
{
    // stride 72 keeps ds_read_b128 16B-aligned, conflicts <=2-way (free)
    __shared__ __align__(16) short lds_h[4][16 * 72];

    const int tid  = threadIdx.x;
    const int wave = tid >> 6;
    const int lane = tid & 63;
    const int l16  = lane & 15;
    const int quad = lane >> 4;

    // W1/W2 in B-operand layout, registers for whole kernel
    bf16x8 w1f[2][4], w2f[2][4];
    #pragma unroll
    for (int ks = 0; ks < 2; ++ks) {
        #pragma unroll
        for (int nt = 0; nt < 4; ++nt) {
            const int col = l16 + 16 * nt;
            const int k0  = quad * 8 + 32 * ks;
            bf16x8 a, b;
            #pragma unroll
            for (int j = 0; j < 8; ++j) {
                a[j] = f2bf(W1[(k0 + j) * 64 + col]);
                b[j] = f2bf(W2[(k0 + j) * 64 + col]);
            }
            w1f[ks][nt] = a;
            w2f[ks][nt] = b;
        }
    }
    float b1v[4], b2v[4];
    #pragma unroll
    for (int nt = 0; nt < 4; ++nt) {
        b1v[nt] = b1[l16 + 16 * nt];
        b2v[nt] = b2[l16 + 16 * nt];
    }

    short* myh = lds_h[wave];
    const int wid = blockIdx.x * 4 + wave;
    const int t0 = wid * tiles_per_wave;
    const int t1 = min(t0 + tiles_per_wave, ntiles);

    for (int t = t0; t < t1; ++t) {
        const int e0 = t * 16;

        // A fragment: row = sorted slot e0+l16 -> edge perm[...], gather rbf row
        const int er = perm[min(e0 + l16, n_edges - 1)];
        const float* rp = rbf + (size_t)er * 64 + quad * 8;
        bf16x8 af[2];
        #pragma unroll
        for (int ks = 0; ks < 2; ++ks) {
            float4 lo = *(const float4*)(rp + 32 * ks);
            float4 hi = *(const float4*)(rp + 32 * ks + 4);
            bf16x8 a;
            a[0] = f2bf(lo.x); a[1] = f2bf(lo.y); a[2] = f2bf(lo.z); a[3] = f2bf(lo.w);
            a[4] = f2bf(hi.x); a[5] = f2bf(hi.y); a[6] = f2bf(hi.z); a[7] = f2bf(hi.w);
            af[ks] = a;
        }

        // GEMM1: H = rbf @ W1
        f32x4 acc[4] = { {0,0,0,0}, {0,0,0,0}, {0,0,0,0}, {0,0,0,0} };
        #pragma unroll
        for (int nt = 0; nt < 4; ++nt)
            #pragma unroll
            for (int ks = 0; ks < 2; ++ks)
                acc[nt] = __builtin_amdgcn_mfma_f32_16x16x32_bf16(
                    af[ks], w1f[ks][nt], acc[nt], 0, 0, 0);

        // bias + softplus, C-layout -> A-layout via LDS
        #pragma unroll
        for (int nt = 0; nt < 4; ++nt)
            #pragma unroll
            for (int r = 0; r < 4; ++r)
                myh[(quad * 4 + r) * 72 + l16 + 16 * nt] =
                    f2bf(ssp(acc[nt][r] + b1v[nt]));

        bf16x8 hf[2];
        #pragma unroll
        for (int ks = 0; ks < 2; ++ks)
            hf[ks] = *(const bf16x8*)(myh + l16 * 72 + quad * 8 + 32 * ks);

        // GEMM2
        f32x4 acc2[4] = { {0,0,0,0}, {0,0,0,0}, {0,0,0,0}, {0,0,0,0} };
        #pragma unroll
        for (int nt = 0; nt < 4; ++nt)
            #pragma unroll
            for (int ks = 0; ks < 2; ++ks)
                acc2[nt] = __builtin_amdgcn_mfma_f32_16x16x32_bf16(
                    hf[ks], w2f[ks][nt], acc2[nt], 0, 0, 0);

        // epilogue: sorted dst -> run-merge a lane's 4 rows before atomics
        int dd[4], ssrc[4];
        #pragma unroll
        for (int r = 0; r < 4; ++r) {
            const int pe = perm[min(e0 + quad * 4 + r, n_edges - 1)];
            dd[r] = dst[pe];
            ssrc[r] = src[pe];
        }
        #pragma unroll
        for (int nt = 0; nt < 4; ++nt) {
            const int col = l16 + 16 * nt;
            float val[4];
            #pragma unroll
            for (int r = 0; r < 4; ++r)
                val[r] = (acc2[nt][r] + b2v[nt]) * nw[(size_t)ssrc[r] * 64 + col];
            float run = val[0];
            int dprev = dd[0];
            #pragma unroll
            for (int r = 1; r < 4; ++r) {
                if (dd[r] == dprev) run += val[r];
                else {
                    atomicAdd(out + (size_t)dprev * 64 + col, run);
                    dprev = dd[r]; run = val[r];
                }
            }
            atomicAdd(out + (size_t)dprev * 64 + col, run);
        }
    }
}

extern "C" void kernel_launch(void* const* d_in, const int* in_sizes, int n_in,
                              void* d_out, int out_size, void* d_ws, size_t ws_size,
                              hipStream_t stream) {
    const float* nw  = (const float*)d_in[0];
    const float* rbf = (const float*)d_in[1];
    const float* W1  = (const float*)d_in[2];
    const float* b1  = (const float*)d_in[3];
    const float* W2  = (const float*)d_in[4];
    const float* b2  = (const float*)d_in[5];
    const int*   src = (const int*)d_in[6];
    const int*   dst = (const int*)d_in[7];
    float* out = (float*)d_out;
    const int n_edges = in_sizes[6];
    const int n_nodes = in_sizes[0] / 64;

    // workspace layout (bytes): cnt[nodes] | cursor[nodes] | partials | perm[edges]
    char* ws = (char*)d_ws;
    int* cnt      = (int*)(ws);
    int* cursor   = (int*)(ws + (size_t)n_nodes * 4);
    int* partials = (int*)(ws + (size_t)n_nodes * 8);
    int* perm     = (int*)(ws + (size_t)n_nodes * 8 + 1024);

    hipMemsetAsync(out, 0, (size_t)out_size * sizeof(float), stream);
    hipMemsetAsync(cnt, 0, (size_t)n_nodes * 4, stream);

    const int nb = (n_nodes + 1023) / 1024;   // scan blocks (98 for 100K, <=256)
    hipLaunchKernelGGL(hist_kernel, dim3((n_edges + 255) / 256), dim3(256), 0, stream,
                       dst, n_edges, cnt);
    hipLaunchKernelGGL(blocksum_kernel, dim3(nb), dim3(256), 0, stream,
                       cnt, n_nodes, partials);
    hipLaunchKernelGGL(scanpart_kernel, dim3(1), dim3(256), 0, stream, partials, nb);
    hipLaunchKernelGGL(scanwrite_kernel, dim3(nb), dim3(256), 0, stream,
                       cnt, n_nodes, partials, cursor);
    hipLaunchKernelGGL(perm_kernel, dim3((n_edges + 255) / 256), dim3(256), 0, stream,
                       dst, n_edges, cursor, perm);

    const int ntiles = (n_edges + 15) / 16;
    const int blocks = 1024;                  // 4096 waves, contiguous tile chunks
    const int tpw = (ntiles + blocks * 4 - 1) / (blocks * 4);
    hipLaunchKernelGGL(cfconv_kernel, dim3(blocks), dim3(256), 0, stream,
                       nw, rbf, W1, b1, W2, b2, src, dst, perm, out,
                       n_edges, ntiles, tpw);
}